// Round 2
// baseline (121.721 us; speedup 1.0000x reference)
//
#include <hip/hip_runtime.h>

#define D_MODEL 256
#define N_HEADS 8
#define MAXN 128    // max neighbors/row; Poisson(32): P(row>128) ~ 1e-40
#define NGEMM 768   // 3 z * 64 by * 4 bx   (64x64 tiles, 3 blocks/CU)

typedef __attribute__((ext_vector_type(8))) short bf16x8;
typedef __attribute__((ext_vector_type(4))) float f32x4;

__device__ __forceinline__ unsigned short f2bf(float f) {
    union { float f; unsigned int u; } v; v.f = f;
    unsigned int r = v.u + 0x7fff + ((v.u >> 16) & 1);   // RNE
    return (unsigned short)(r >> 16);
}
__device__ __forceinline__ float bf2f(unsigned short u) {
    union { unsigned int u; float f; } v; v.u = ((unsigned int)u) << 16;
    return v.f;
}

// ---------------------------------------------------------------------------
// prep: mask init (zeros + diagonal) + weight fp32->bf16 converts.
// (xb eliminated: qkv GEMM inline-converts its A tile from fp32 x.)
// ---------------------------------------------------------------------------
__global__ void prep_kernel(const float* __restrict__ W0, const float* __restrict__ W1,
                            const float* __restrict__ W2, const float* __restrict__ W3,
                            unsigned short* __restrict__ O0, unsigned short* __restrict__ O1,
                            unsigned short* __restrict__ O2, unsigned short* __restrict__ O3,
                            unsigned long long* __restrict__ mask, int n) {
    int i = blockIdx.x * blockDim.x + threadIdx.x;

    int wpr = n >> 6;
    int mwords = n * wpr;
    if (i < mwords) {
        int row = i >> 6;                     // wpr == 64
        int w = i & 63;
        mask[i] = (w == (row >> 6)) ? (1ULL << (row & 63)) : 0ULL;
    }
    if (i < 4 * 16384) {
        int z = i >> 14;
        int k = i & 16383;
        const float* src = (z == 0) ? W0 : (z == 1) ? W1 : (z == 2) ? W2 : W3;
        unsigned short* dst = (z == 0) ? O0 : (z == 1) ? O1 : (z == 2) ? O2 : O3;
        float4 v = *(const float4*)(src + (size_t)k * 4);
        ushort4 o;
        o.x = f2bf(v.x); o.y = f2bf(v.y); o.z = f2bf(v.z); o.w = f2bf(v.w);
        *(ushort4*)(dst + (size_t)k * 4) = o;
    }
}

// ---------------------------------------------------------------------------
// Fused: QKV GEMM (blocks 0..NGEMM-1) + edge-mask atomicOr (blocks NGEMM..).
// GEMM: C = x @ W^T, A inline-converted fp32->bf16 during staging.
// BM=64, BN=64, BK=64 -> 768 blocks = 3/CU (was 384 = 1.5/CU: tail-bound).
// ---------------------------------------------------------------------------
__global__ __launch_bounds__(256) void qkv_edges_kernel(
        const float* __restrict__ x,
        const unsigned short* __restrict__ Wq, const unsigned short* __restrict__ Wk,
        const unsigned short* __restrict__ Wv,
        unsigned short* __restrict__ Qb, unsigned short* __restrict__ Kb,
        unsigned short* __restrict__ Vb,
        const int* __restrict__ ei, unsigned long long* __restrict__ mask,
        int E, int n) {
    int blk = blockIdx.x;
    if (blk >= NGEMM) {
        int e = (blk - NGEMM) * 256 + threadIdx.x;
        if (e < E) {
            int src = ei[e];
            int dst = ei[E + e];
            int wpr = n >> 6;
            atomicOr(&mask[(size_t)dst * wpr + (src >> 6)], 1ULL << (src & 63));
        }
        return;
    }
    int z = blk >> 8;                 // 3 * 256
    int r = blk & 255;
    int by = r >> 2, bx = r & 3;
    const unsigned short* B = (z == 0) ? Wq : (z == 1) ? Wk : Wv;
    unsigned short* Cb = (z == 0) ? Qb : (z == 1) ? Kb : Vb;

    __shared__ short Alds[64][72];    // +8 pad
    __shared__ short Blds[64][72];
    int t = threadIdx.x;
    int wave = t >> 6, lane = t & 63;
    int wr = wave >> 1, wc = wave & 1;
    int sr = t >> 2;                  // stage row 0..63
    int sc = (t & 3) << 4;            // stage col {0,16,32,48}

    const float* Abase = x + (size_t)(by * 64 + sr) * D_MODEL + sc;
    const unsigned short* Bbase = B + (size_t)(bx * 64 + sr) * D_MODEL + sc;

    int fm = lane & 15;
    int fk = (lane >> 4) << 3;

    f32x4 acc[2][2];
#pragma unroll
    for (int rr = 0; rr < 2; ++rr)
#pragma unroll
        for (int c = 0; c < 2; ++c) acc[rr][c] = (f32x4){0.f, 0.f, 0.f, 0.f};

    for (int k0 = 0; k0 < D_MODEL; k0 += 64) {
        float4 a0 = *(const float4*)(Abase + k0);
        float4 a1 = *(const float4*)(Abase + k0 + 4);
        float4 a2 = *(const float4*)(Abase + k0 + 8);
        float4 a3 = *(const float4*)(Abase + k0 + 12);
        ushort4 u0, u1, u2, u3;
        u0.x = f2bf(a0.x); u0.y = f2bf(a0.y); u0.z = f2bf(a0.z); u0.w = f2bf(a0.w);
        u1.x = f2bf(a1.x); u1.y = f2bf(a1.y); u1.z = f2bf(a1.z); u1.w = f2bf(a1.w);
        u2.x = f2bf(a2.x); u2.y = f2bf(a2.y); u2.z = f2bf(a2.z); u2.w = f2bf(a2.w);
        u3.x = f2bf(a3.x); u3.y = f2bf(a3.y); u3.z = f2bf(a3.z); u3.w = f2bf(a3.w);
        *(ushort4*)&Alds[sr][sc]      = u0;
        *(ushort4*)&Alds[sr][sc + 4]  = u1;
        *(ushort4*)&Alds[sr][sc + 8]  = u2;
        *(ushort4*)&Alds[sr][sc + 12] = u3;
        *(uint4*)&Blds[sr][sc]     = *(const uint4*)(Bbase + k0);
        *(uint4*)&Blds[sr][sc + 8] = *(const uint4*)(Bbase + k0 + 8);
        __syncthreads();
#pragma unroll
        for (int ks = 0; ks < 64; ks += 32) {
            bf16x8 af[2], bfr[2];
#pragma unroll
            for (int rr = 0; rr < 2; ++rr)
                af[rr] = *(const bf16x8*)&Alds[wr * 32 + rr * 16 + fm][ks + fk];
#pragma unroll
            for (int c = 0; c < 2; ++c)
                bfr[c] = *(const bf16x8*)&Blds[wc * 32 + c * 16 + fm][ks + fk];
#pragma unroll
            for (int rr = 0; rr < 2; ++rr)
#pragma unroll
                for (int c = 0; c < 2; ++c)
                    acc[rr][c] = __builtin_amdgcn_mfma_f32_16x16x32_bf16(
                        af[rr], bfr[c], acc[rr][c], 0, 0, 0);
        }
        __syncthreads();
    }

    int orow0 = by * 64 + wr * 32 + ((lane >> 4) << 2);
    int ocol0 = bx * 64 + wc * 32 + (lane & 15);
#pragma unroll
    for (int rr = 0; rr < 2; ++rr)
#pragma unroll
        for (int c = 0; c < 2; ++c)
#pragma unroll
            for (int q = 0; q < 4; ++q)
                Cb[(size_t)(orow0 + rr * 16 + q) * D_MODEL + ocol0 + c * 16] =
                    f2bf(acc[rr][c][q]);
}

// ---------------------------------------------------------------------------
// Sparse attention, SINGLE-PASS online-softmax, register-resident pipeline.
// One wave per dst. R1 change: weight redistribution (score lanes -> PV lanes)
// via wave-internal LDS transpose (bank-padded w_t[8][20]) instead of 18
// ds_bpermute per tile. Same wave -> DS pipe is in-order -> no barrier, so
// the V-gather / K-prefetch pipeline stays in flight across the whole tile.
// ---------------------------------------------------------------------------
#define LOAD_K(KR, tt)                                                        \
    do {                                                                      \
        int _ti = (tt);                                                       \
        if (_ti < nt) {                                                       \
            int _ix = nbr[_ti * 16 + col];                                    \
            const unsigned short* _kr = Kb + _ix * D_MODEL + (kq << 3);       \
            KR[0] = *(const bf16x8*)(_kr + 0 * 32);                           \
            KR[1] = *(const bf16x8*)(_kr + 1 * 32);                           \
            KR[2] = *(const bf16x8*)(_kr + 2 * 32);                           \
            KR[3] = *(const bf16x8*)(_kr + 3 * 32);                           \
            KR[4] = *(const bf16x8*)(_kr + 4 * 32);                           \
            KR[5] = *(const bf16x8*)(_kr + 5 * 32);                           \
            KR[6] = *(const bf16x8*)(_kr + 6 * 32);                           \
            KR[7] = *(const bf16x8*)(_kr + 7 * 32);                           \
        }                                                                     \
    } while (0)

#define FMA4(P, W, V)                                                         \
    do {                                                                      \
        P[0] += (W) * bf2f((unsigned short)((V).x & 0xffff));                 \
        P[1] += (W) * bf2f((unsigned short)((V).x >> 16));                    \
        P[2] += (W) * bf2f((unsigned short)((V).y & 0xffff));                 \
        P[3] += (W) * bf2f((unsigned short)((V).y >> 16));                    \
    } while (0)

#define TILE_BODY(KC, KN, tt)                                                 \
    do {                                                                      \
        int _t = (tt);                                                        \
        int _b0 = _t << 4;                                                    \
        int4 _i0 = *(const int4*)&nbr[_b0];                                   \
        int4 _i1 = *(const int4*)&nbr[_b0 + 4];                               \
        int4 _i2 = *(const int4*)&nbr[_b0 + 8];                               \
        int4 _i3 = *(const int4*)&nbr[_b0 + 12];                              \
        /* issue all V gathers for this tile NOW (consumed after softmax) */  \
        uint2 _v0  = *(const uint2*)(vbase + _i0.x * D_MODEL);                \
        uint2 _v1  = *(const uint2*)(vbase + _i0.y * D_MODEL);                \
        uint2 _v2  = *(const uint2*)(vbase + _i0.z * D_MODEL);                \
        uint2 _v3  = *(const uint2*)(vbase + _i0.w * D_MODEL);                \
        uint2 _v4  = *(const uint2*)(vbase + _i1.x * D_MODEL);                \
        uint2 _v5  = *(const uint2*)(vbase + _i1.y * D_MODEL);                \
        uint2 _v6  = *(const uint2*)(vbase + _i1.z * D_MODEL);                \
        uint2 _v7  = *(const uint2*)(vbase + _i1.w * D_MODEL);                \
        uint2 _v8  = *(const uint2*)(vbase + _i2.x * D_MODEL);                \
        uint2 _v9  = *(const uint2*)(vbase + _i2.y * D_MODEL);                \
        uint2 _v10 = *(const uint2*)(vbase + _i2.z * D_MODEL);                \
        uint2 _v11 = *(const uint2*)(vbase + _i2.w * D_MODEL);                \
        uint2 _v12 = *(const uint2*)(vbase + _i3.x * D_MODEL);                \
        uint2 _v13 = *(const uint2*)(vbase + _i3.y * D_MODEL);                \
        uint2 _v14 = *(const uint2*)(vbase + _i3.z * D_MODEL);                \
        uint2 _v15 = *(const uint2*)(vbase + _i3.w * D_MODEL);                \
        /* prefetch next K tile (consumed next iteration) */                  \
        LOAD_K(KN, _t + 1);                                                   \
        f32x4 _c0 = (f32x4){0.f, 0.f, 0.f, 0.f};                              \
        f32x4 _c1 = (f32x4){0.f, 0.f, 0.f, 0.f};                              \
        _c0 = __builtin_amdgcn_mfma_f32_16x16x32_bf16(KC[0], (col == 0) ? qf : zf, _c0, 0, 0, 0); \
        _c1 = __builtin_amdgcn_mfma_f32_16x16x32_bf16(KC[1], (col == 1) ? qf : zf, _c1, 0, 0, 0); \
        _c0 = __builtin_amdgcn_mfma_f32_16x16x32_bf16(KC[2], (col == 2) ? qf : zf, _c0, 0, 0, 0); \
        _c1 = __builtin_amdgcn_mfma_f32_16x16x32_bf16(KC[3], (col == 3) ? qf : zf, _c1, 0, 0, 0); \
        _c0 = __builtin_amdgcn_mfma_f32_16x16x32_bf16(KC[4], (col == 4) ? qf : zf, _c0, 0, 0, 0); \
        _c1 = __builtin_amdgcn_mfma_f32_16x16x32_bf16(KC[5], (col == 5) ? qf : zf, _c1, 0, 0, 0); \
        _c0 = __builtin_amdgcn_mfma_f32_16x16x32_bf16(KC[6], (col == 6) ? qf : zf, _c0, 0, 0, 0); \
        _c1 = __builtin_amdgcn_mfma_f32_16x16x32_bf16(KC[7], (col == 7) ? qf : zf, _c1, 0, 0, 0); \
        float _s0 = (_c0[0] + _c1[0]) * inv_scale;                            \
        float _s1 = (_c0[1] + _c1[1]) * inv_scale;                            \
        float _s2 = (_c0[2] + _c1[2]) * inv_scale;                            \
        float _s3 = (_c0[3] + _c1[3]) * inv_scale;                            \
        int _jr = _b0 + (kq << 2);                                            \
        _s0 = (_jr + 0 < cnt) ? _s0 : -1e30f;                                 \
        _s1 = (_jr + 1 < cnt) ? _s1 : -1e30f;                                 \
        _s2 = (_jr + 2 < cnt) ? _s2 : -1e30f;                                 \
        _s3 = (_jr + 3 < cnt) ? _s3 : -1e30f;                                 \
        /* tile max + sum per head (reduce across the 4 kq lanes of col) */   \
        float _mt = fmaxf(fmaxf(_s0, _s1), fmaxf(_s2, _s3));                  \
        _mt = fmaxf(_mt, __shfl_xor(_mt, 16, 64));                            \
        _mt = fmaxf(_mt, __shfl_xor(_mt, 32, 64));                            \
        float _w0 = __expf(_s0 - _mt);                                        \
        float _w1 = __expf(_s1 - _mt);                                        \
        float _w2 = __expf(_s2 - _mt);                                        \
        float _w3 = __expf(_s3 - _mt);                                        \
        float _ts = (_w0 + _w1) + (_w2 + _w3);                                \
        _ts += __shfl_xor(_ts, 16, 64);                                       \
        _ts += __shfl_xor(_ts, 32, 64);                                       \
        /* stash weights + (m,t) to LDS (same wave: in-order, no barrier) */  \
        if (col < N_HEADS) {                                                  \
            float4 _wq; _wq.x = _w0; _wq.y = _w1; _wq.z = _w2; _wq.w = _w3;   \
            *(float4*)&w_t[col][kq << 2] = _wq;                               \
            if (kq == 0) { float2 _ax2; _ax2.x = _mt; _ax2.y = _ts;           \
                           aux2[col] = _ax2; }                                \
        }                                                                     \
        float2 _ax = aux2[h];                                                 \
        float _mn = fmaxf(m, _ax.x);                                          \
        float _so = __expf(m - _mn);                                          \
        float _f  = __expf(_ax.x - _mn);                                      \
        m = _mn;                                                              \
        l = l * _so + _ax.y * _f;                                             \
        float4 _wA = *(const float4*)&w_t[h][0];                              \
        float4 _wB = *(const float4*)&w_t[h][4];                              \
        float4 _wC = *(const float4*)&w_t[h][8];                              \
        float4 _wD = *(const float4*)&w_t[h][12];                             \
        f32x4 _p = (f32x4){0.f, 0.f, 0.f, 0.f};                               \
        FMA4(_p, _wA.x, _v0);  FMA4(_p, _wA.y, _v1);                          \
        FMA4(_p, _wA.z, _v2);  FMA4(_p, _wA.w, _v3);                          \
        FMA4(_p, _wB.x, _v4);  FMA4(_p, _wB.y, _v5);                          \
        FMA4(_p, _wB.z, _v6);  FMA4(_p, _wB.w, _v7);                          \
        FMA4(_p, _wC.x, _v8);  FMA4(_p, _wC.y, _v9);                          \
        FMA4(_p, _wC.z, _v10); FMA4(_p, _wC.w, _v11);                         \
        FMA4(_p, _wD.x, _v12); FMA4(_p, _wD.y, _v13);                         \
        FMA4(_p, _wD.z, _v14); FMA4(_p, _wD.w, _v15);                         \
        acc[0] = acc[0] * _so + _p[0] * _f;                                   \
        acc[1] = acc[1] * _so + _p[1] * _f;                                   \
        acc[2] = acc[2] * _so + _p[2] * _f;                                   \
        acc[3] = acc[3] * _so + _p[3] * _f;                                   \
    } while (0)

__global__ __launch_bounds__(64) void attn_kernel(
        const unsigned short* __restrict__ Qb, const unsigned short* __restrict__ Kb,
        const unsigned short* __restrict__ Vb,
        const unsigned long long* __restrict__ mask,
        unsigned short* __restrict__ Ob, int n) {
    int dst = blockIdx.x;
    int L = threadIdx.x;
    int wpr = n >> 6;

    __shared__ alignas(16) int nbr[MAXN + 16];
    __shared__ float w_t[N_HEADS][20];   // [8][20]: rows land on distinct banks
    __shared__ float2 aux2[N_HEADS];

    // ---- Phase A: neighbor enumeration ----
    unsigned long long w = (L < wpr) ? mask[(size_t)dst * wpr + L] : 0ULL;
    int c = __popcll(w);
    int xs = c;
#pragma unroll
    for (int o = 1; o < 64; o <<= 1) {
        int y = __shfl_up(xs, o, 64);
        if (L >= o) xs += y;
    }
    int pos = xs - c;
    while (w) {
        int b = __builtin_ctzll(w);
        w &= w - 1;
        if (pos < MAXN) nbr[pos] = (L << 6) + b;
        ++pos;
    }
    int cnt = __shfl(xs, 63, 64);
    if (cnt > MAXN) cnt = MAXN;
    int nb = (cnt + 15) & ~15;
    __syncthreads();
    int last = nbr[cnt - 1];
    if (L < nb - cnt) nbr[cnt + L] = last;   // pad; padded scores forced to -1e30
    __syncthreads();
    int nt = nb >> 4;

    // score-lane config (col = neighbor slot / head column, kq = k-quarter)
    int col = L & 15;
    int kq = L >> 4;
    bf16x8 qf = (bf16x8){0, 0, 0, 0, 0, 0, 0, 0};
    if (col < N_HEADS)
        qf = *(const bf16x8*)(Qb + (size_t)dst * D_MODEL + col * 32 + kq * 8);
    const bf16x8 zf = (bf16x8){0, 0, 0, 0, 0, 0, 0, 0};
    const float inv_scale = 0.17677669529663687f;   // 1/sqrt(32)

    // PV-lane config: head h, dims 4L..4L+3
    int h = L >> 3;
    const unsigned short* vbase = Vb + 4 * L;

    float m = -1e30f, l = 0.f;
    f32x4 acc = (f32x4){0.f, 0.f, 0.f, 0.f};

    bf16x8 KA[8], KBx[8];
    LOAD_K(KA, 0);
    for (int t = 0; t < nt; t += 2) {
        TILE_BODY(KA, KBx, t);
        if (t + 1 < nt) TILE_BODY(KBx, KA, t + 1);
    }

    float rl = 1.f / l;
    ushort4 o;
    o.x = f2bf(acc[0] * rl); o.y = f2bf(acc[1] * rl);
    o.z = f2bf(acc[2] * rl); o.w = f2bf(acc[3] * rl);
    *(ushort4*)(Ob + (size_t)dst * D_MODEL + 4 * L) = o;
}

// ---------------------------------------------------------------------------
// Fused output GEMM + residual + bias + LayerNorm.
// BM=16, BN=256 (full row), BK=64 -> 256 blocks = 1/CU (was 128 = 0.5/CU).
// ---------------------------------------------------------------------------
struct SMemO {
    union {
        struct { short A[16][72]; short B[256][72]; } st;
        float c[16][260];
    };
};

__global__ __launch_bounds__(256) void gemm_o_ln_kernel(
        const unsigned short* __restrict__ Ob, const unsigned short* __restrict__ Wob,
        const float* __restrict__ x, const float* __restrict__ bo,
        const float* __restrict__ gamma, const float* __restrict__ beta,
        float* __restrict__ out) {
    __shared__ SMemO sm;
    int by = blockIdx.x;
    int t = threadIdx.x;
    int wave = t >> 6, lane = t & 63;
    int ar = t >> 4;                  // A-stage row 0..15
    int ac = (t & 15) << 2;           // A-stage col {0,4,...,60}
    int lr = t >> 3;                  // B-stage row 0..31
    int lk = (t & 7) << 3;

    const unsigned short* Abase = Ob + ((size_t)(by * 16 + ar)) * D_MODEL + ac;
    int fm = lane & 15;
    int fk = (lane >> 4) << 3;

    f32x4 acc[4];
#pragma unroll
    for (int ct = 0; ct < 4; ++ct) acc[ct] = (f32x4){0.f, 0.f, 0.f, 0.f};

    for (int k0 = 0; k0 < D_MODEL; k0 += 64) {
        *(ushort4*)&sm.st.A[ar][ac] = *(const ushort4*)(Abase + k0);
#pragma unroll
        for (int j = 0; j < 8; ++j)
            *(uint4*)&sm.st.B[lr + 32 * j][lk] =
                *(const uint4*)(Wob + ((size_t)(lr + 32 * j)) * D_MODEL + k0 + lk);
        __syncthreads();
#pragma unroll
        for (int ks = 0; ks < 64; ks += 32) {
            bf16x8 af = *(const bf16x8*)&sm.st.A[fm][ks + fk];
#pragma unroll
            for (int ct = 0; ct < 4; ++ct) {
                bf16x8 bfr = *(const bf16x8*)&sm.st.B[wave * 64 + ct * 16 + fm][ks + fk];
                acc[ct] = __builtin_amdgcn_mfma_f32_16x16x32_bf16(af, bfr, acc[ct], 0, 0, 0);
            }
        }
        __syncthreads();
    }

    int rr0 = (lane >> 4) << 2;
#pragma unroll
    for (int ct = 0; ct < 4; ++ct)
#pragma unroll
        for (int q = 0; q < 4; ++q)
            sm.c[rr0 + q][wave * 64 + ct * 16 + (lane & 15)] = acc[ct][q];
    __syncthreads();

    float4 bo4 = *(const float4*)(bo + lane * 4);
    float4 g4  = *(const float4*)(gamma + lane * 4);
    float4 be4 = *(const float4*)(beta + lane * 4);
#pragma unroll
    for (int rr = 0; rr < 4; ++rr) {
        int r = wave * 4 + rr;
        int grow = by * 16 + r;
        float4 p = *(const float4*)&sm.c[r][lane * 4];
        float4 xv = *(const float4*)(x + (size_t)grow * D_MODEL + lane * 4);
        float hx = p.x + xv.x + bo4.x;
        float hy = p.y + xv.y + bo4.y;
        float hz = p.z + xv.z + bo4.z;
        float hw = p.w + xv.w + bo4.w;
        float s  = (hx + hy) + (hz + hw);
        float s2 = (hx * hx + hy * hy) + (hz * hz + hw * hw);
#pragma unroll
        for (int o = 32; o; o >>= 1) {
            s  += __shfl_xor(s, o, 64);
            s2 += __shfl_xor(s2, o, 64);
        }
        float mu = s * (1.f / 256.f);
        float var = s2 * (1.f / 256.f) - mu * mu;
        float rstd = rsqrtf(var + 1e-5f);
        float4 o4;
        o4.x = (hx - mu) * rstd * g4.x + be4.x;
        o4.y = (hy - mu) * rstd * g4.y + be4.y;
        o4.z = (hz - mu) * rstd * g4.z + be4.z;
        o4.w = (hw - mu) * rstd * g4.w + be4.w;
        *(float4*)(out + (size_t)grow * D_MODEL + lane * 4) = o4;
    }
}

// ---------------------------------------------------------------------------
extern "C" void kernel_launch(void* const* d_in, const int* in_sizes, int n_in,
                              void* d_out, int out_size, void* d_ws, size_t ws_size,
                              hipStream_t stream) {
    const float* x     = (const float*)d_in[0];
    const int*   ei    = (const int*)  d_in[1];
    const float* Wq    = (const float*)d_in[2];
    const float* Wk    = (const float*)d_in[3];
    const float* Wv    = (const float*)d_in[4];
    const float* Wo    = (const float*)d_in[5];
    const float* bo    = (const float*)d_in[6];
    const float* gamma = (const float*)d_in[7];
    const float* beta  = (const float*)d_in[8];
    float* out = (float*)d_out;

    int n = in_sizes[0] / D_MODEL;   // 4096
    int E = in_sizes[1] / 2;         // 131072

    char* ws = (char*)d_ws;
    size_t off = 0;
    unsigned long long* mask = (unsigned long long*)(ws + off);
    off += (size_t)n * (n >> 6) * sizeof(unsigned long long);          // 2 MiB
    unsigned short* Wqb = (unsigned short*)(ws + off); off += D_MODEL * D_MODEL * 2;
    unsigned short* Wkb = (unsigned short*)(ws + off); off += D_MODEL * D_MODEL * 2;
    unsigned short* Wvb = (unsigned short*)(ws + off); off += D_MODEL * D_MODEL * 2;
    unsigned short* Wob = (unsigned short*)(ws + off); off += D_MODEL * D_MODEL * 2;
    unsigned short* Qb  = (unsigned short*)(ws + off); off += (size_t)n * D_MODEL * 2;
    unsigned short* Kb  = (unsigned short*)(ws + off); off += (size_t)n * D_MODEL * 2;
    unsigned short* Vb  = (unsigned short*)(ws + off); off += (size_t)n * D_MODEL * 2;
    unsigned short* Ob  = (unsigned short*)(ws + off); off += (size_t)n * D_MODEL * 2;

    // 1) prep: mask init (diag) + weight converts (xb eliminated)
    int mwords = n * (n >> 6);
    prep_kernel<<<(mwords + 255) / 256, 256, 0, stream>>>(
        Wq, Wk, Wv, Wo, Wqb, Wkb, Wvb, Wob, mask, n);

    // 2) fused QKV GEMM (inline A-convert from fp32 x) + edge scatter
    int edge_blocks = (E + 255) / 256;       // 512
    qkv_edges_kernel<<<NGEMM + edge_blocks, 256, 0, stream>>>(
        x, Wqb, Wkb, Wvb, Qb, Kb, Vb, ei, mask, E, n);

    // 3) sparse attention: one wave per dst, single-pass online softmax
    attn_kernel<<<n, 64, 0, stream>>>(Qb, Kb, Vb, mask, Ob, n);

    // 4) output GEMM + residual + LayerNorm
    gemm_o_ln_kernel<<<n / 16, 256, 0, stream>>>(Ob, Wob, x, bo, gamma, beta, out);
}

// Round 3
// 113.928 us; speedup vs baseline: 1.0684x; 1.0684x over previous
//
#include <hip/hip_runtime.h>

#define D_MODEL 256
#define N_HEADS 8
#define MAXN 128    // max neighbors/row; Poisson(32): P(row>128) ~ 1e-40
#define NGEMM 384   // 3 z * 32 by * 4 bx  (128x64 tiles -- measured best)
#define NCONV 16    // Wo fp32->bf16 convert blocks

typedef __attribute__((ext_vector_type(8))) short bf16x8;
typedef __attribute__((ext_vector_type(4))) float f32x4;

__device__ __forceinline__ unsigned short f2bf(float f) {
    union { float f; unsigned int u; } v; v.f = f;
    unsigned int r = v.u + 0x7fff + ((v.u >> 16) & 1);   // RNE
    return (unsigned short)(r >> 16);
}
__device__ __forceinline__ float bf2f(unsigned short u) {
    union { unsigned int u; float f; } v; v.u = ((unsigned int)u) << 16;
    return v.f;
}
__device__ __forceinline__ ushort4 cvt4(float4 v) {
    ushort4 o;
    o.x = f2bf(v.x); o.y = f2bf(v.y); o.z = f2bf(v.z); o.w = f2bf(v.w);
    return o;
}

// ---------------------------------------------------------------------------
// Fused: QKV GEMM (blocks 0..NGEMM-1, inline fp32->bf16 of x and W tiles)
//      + Wo convert (NCONV blocks) + edge-mask atomicOr (rest).
// GEMM: C = x @ W^T. BM=128, BN=64, BK=64 (proven best tiling, 28 KB LDS).
// mask was zeroed by hipMemsetAsync; diag bits OR'd inline in attn.
// ---------------------------------------------------------------------------
__global__ __launch_bounds__(256) void qkv_edges_kernel(
        const float* __restrict__ x,
        const float* __restrict__ Wq, const float* __restrict__ Wk,
        const float* __restrict__ Wv, const float* __restrict__ Wo,
        unsigned short* __restrict__ Qb, unsigned short* __restrict__ Kb,
        unsigned short* __restrict__ Vb, unsigned short* __restrict__ Wob,
        const int* __restrict__ ei, unsigned long long* __restrict__ mask,
        int E, int n) {
    int blk = blockIdx.x;
    if (blk >= NGEMM) {
        int b2 = blk - NGEMM;
        if (b2 < NCONV) {
            // Wo (65536 fp32) -> Wob bf16: 16 blocks * 256 thr * 16 floats
            int i = (b2 * 256 + threadIdx.x) * 16;
            const float* s = Wo + i;
            unsigned short* d = Wob + i;
#pragma unroll
            for (int j = 0; j < 4; ++j)
                *(ushort4*)(d + 4 * j) = cvt4(*(const float4*)(s + 4 * j));
            return;
        }
        int e = (b2 - NCONV) * 256 + threadIdx.x;
        if (e < E) {
            int src = ei[e];
            int dst = ei[E + e];
            int wpr = n >> 6;
            atomicOr(&mask[(size_t)dst * wpr + (src >> 6)], 1ULL << (src & 63));
        }
        return;
    }
    int z = blk >> 7;
    int r = blk & 127;
    int by = r >> 2, bx = r & 3;
    const float* B = (z == 0) ? Wq : (z == 1) ? Wk : Wv;
    unsigned short* Cb = (z == 0) ? Qb : (z == 1) ? Kb : Vb;

    __shared__ short Alds[128][72];   // +8 pad
    __shared__ short Blds[64][72];
    int t = threadIdx.x;
    int wave = t >> 6, lane = t & 63;
    int wr = wave >> 1, wc = wave & 1;
    int lr = t >> 3;
    int lk = (t & 7) << 3;

    const float* Abase = x + ((size_t)(by * 128 + lr)) * D_MODEL + lk;
    const float* Bbase = B + ((size_t)(bx * 64 + lr)) * D_MODEL + lk;

    int fm = lane & 15;
    int fk = (lane >> 4) << 3;

    f32x4 acc[4][2];
#pragma unroll
    for (int rr = 0; rr < 4; ++rr)
#pragma unroll
        for (int c = 0; c < 2; ++c) acc[rr][c] = (f32x4){0.f, 0.f, 0.f, 0.f};

    for (int k0 = 0; k0 < D_MODEL; k0 += 64) {
#pragma unroll
        for (int j = 0; j < 4; ++j) {
            float4 va = *(const float4*)(Abase + (size_t)j * 32 * D_MODEL + k0);
            float4 vb = *(const float4*)(Abase + (size_t)j * 32 * D_MODEL + k0 + 4);
            *(ushort4*)&Alds[lr + 32 * j][lk]     = cvt4(va);
            *(ushort4*)&Alds[lr + 32 * j][lk + 4] = cvt4(vb);
        }
#pragma unroll
        for (int j = 0; j < 2; ++j) {
            float4 va = *(const float4*)(Bbase + (size_t)j * 32 * D_MODEL + k0);
            float4 vb = *(const float4*)(Bbase + (size_t)j * 32 * D_MODEL + k0 + 4);
            *(ushort4*)&Blds[lr + 32 * j][lk]     = cvt4(va);
            *(ushort4*)&Blds[lr + 32 * j][lk + 4] = cvt4(vb);
        }
        __syncthreads();
#pragma unroll
        for (int ks = 0; ks < 64; ks += 32) {
            bf16x8 af[4], bf[2];
#pragma unroll
            for (int rr = 0; rr < 4; ++rr)
                af[rr] = *(const bf16x8*)&Alds[wr * 64 + rr * 16 + fm][ks + fk];
#pragma unroll
            for (int c = 0; c < 2; ++c)
                bf[c] = *(const bf16x8*)&Blds[wc * 32 + c * 16 + fm][ks + fk];
#pragma unroll
            for (int rr = 0; rr < 4; ++rr)
#pragma unroll
                for (int c = 0; c < 2; ++c)
                    acc[rr][c] = __builtin_amdgcn_mfma_f32_16x16x32_bf16(
                        af[rr], bf[c], acc[rr][c], 0, 0, 0);
        }
        __syncthreads();
    }

    int orow0 = by * 128 + wr * 64 + ((lane >> 4) << 2);
    int ocol0 = bx * 64 + wc * 32 + (lane & 15);
#pragma unroll
    for (int rr = 0; rr < 4; ++rr)
#pragma unroll
        for (int c = 0; c < 2; ++c)
#pragma unroll
            for (int q = 0; q < 4; ++q)
                Cb[(size_t)(orow0 + rr * 16 + q) * D_MODEL + ocol0 + c * 16] =
                    f2bf(acc[rr][c][q]);
}

// ---------------------------------------------------------------------------
// Sparse attention, two-pass, MFMA-scored. One wave (64 thr) per dst.
// (Proven-best R5 structure from prior session; diag bit OR'd inline.)
// ---------------------------------------------------------------------------
__global__ __launch_bounds__(64) void attn_kernel(
        const unsigned short* __restrict__ Qb, const unsigned short* __restrict__ Kb,
        const unsigned short* __restrict__ Vb,
        const unsigned long long* __restrict__ mask,
        unsigned short* __restrict__ Ob, int n) {
    int dst = blockIdx.x;
    int L = threadIdx.x;
    int wpr = n >> 6;

    __shared__ int nbr[MAXN + 16];
    __shared__ float s_lds[N_HEADS][MAXN];

    // ---- Phase A: neighbor enumeration ----
    unsigned long long w = (L < wpr) ? mask[(size_t)dst * wpr + L] : 0ULL;
    if (L == (dst >> 6)) w |= 1ULL << (dst & 63);      // diagonal inline
    int c = __popcll(w);
    int xs = c;
#pragma unroll
    for (int o = 1; o < 64; o <<= 1) {
        int y = __shfl_up(xs, o, 64);
        if (L >= o) xs += y;
    }
    int pos = xs - c;
    while (w) {
        int b = __builtin_ctzll(w);
        w &= w - 1;
        if (pos < MAXN) nbr[pos] = (L << 6) + b;
        ++pos;
    }
    int cnt = __shfl(xs, 63, 64);
    if (cnt > MAXN) cnt = MAXN;
    int nb = (cnt + 15) & ~15;
    __syncthreads();
    int last = nbr[cnt - 1];
    if (L < nb - cnt) nbr[cnt + L] = last;   // pad; padded scores forced to -1e30
    __syncthreads();

    // per-lane Q fragment (col = head for col<8, else zero)
    int col = L & 15;
    int kq = L >> 4;
    bf16x8 qf = (bf16x8){0, 0, 0, 0, 0, 0, 0, 0};
    if (col < N_HEADS)
        qf = *(const bf16x8*)(Qb + (size_t)dst * D_MODEL + col * 32 + kq * 8);
    const bf16x8 zf = (bf16x8){0, 0, 0, 0, 0, 0, 0, 0};
    const float inv_scale = 0.17677669529663687f;   // 1/sqrt(32)

    // ---- Phase B: scores via MFMA (head-masked B trick) ----
    for (int b0 = 0; b0 < nb; b0 += 16) {
        int nj = nbr[b0 + col];
        const unsigned short* krow = Kb + (size_t)nj * D_MODEL + kq * 8;
        f32x4 c0 = (f32x4){0.f, 0.f, 0.f, 0.f};
        f32x4 c1 = (f32x4){0.f, 0.f, 0.f, 0.f};
#pragma unroll
        for (int kb = 0; kb < 8; kb += 2) {
            bf16x8 a0 = *(const bf16x8*)(krow + kb * 32);
            bf16x8 a1 = *(const bf16x8*)(krow + kb * 32 + 32);
            bf16x8 bop0 = (col == kb)     ? qf : zf;
            bf16x8 bop1 = (col == kb + 1) ? qf : zf;
            c0 = __builtin_amdgcn_mfma_f32_16x16x32_bf16(a0, bop0, c0, 0, 0, 0);
            c1 = __builtin_amdgcn_mfma_f32_16x16x32_bf16(a1, bop1, c1, 0, 0, 0);
        }
        if (col < N_HEADS) {
            int jr = b0 + kq * 4;
            float4 o4;
            float s0 = (c0[0] + c1[0]) * inv_scale;
            float s1 = (c0[1] + c1[1]) * inv_scale;
            float s2 = (c0[2] + c1[2]) * inv_scale;
            float s3 = (c0[3] + c1[3]) * inv_scale;
            o4.x = (jr + 0 < cnt) ? s0 : -1e30f;
            o4.y = (jr + 1 < cnt) ? s1 : -1e30f;
            o4.z = (jr + 2 < cnt) ? s2 : -1e30f;
            o4.w = (jr + 3 < cnt) ? s3 : -1e30f;
            *(float4*)&s_lds[col][jr] = o4;
        }
    }
    __syncthreads();

    // ---- Phase C: softmax (h = L>>3, 8 lanes per head) ----
    int h = L >> 3, li = L & 7;
    float m = -1e30f;
    for (int j0 = li * 4; j0 < nb; j0 += 32) {
        float4 v = *(const float4*)&s_lds[h][j0];
        m = fmaxf(m, fmaxf(fmaxf(v.x, v.y), fmaxf(v.z, v.w)));
    }
    m = fmaxf(m, __shfl_xor(m, 1, 8));
    m = fmaxf(m, __shfl_xor(m, 2, 8));
    m = fmaxf(m, __shfl_xor(m, 4, 8));
    float l = 0.f;
    for (int j0 = li * 4; j0 < nb; j0 += 32) {
        float4 v = *(const float4*)&s_lds[h][j0];
        float4 e4;
        e4.x = __expf(v.x - m); e4.y = __expf(v.y - m);
        e4.z = __expf(v.z - m); e4.w = __expf(v.w - m);
        *(float4*)&s_lds[h][j0] = e4;
        l += (e4.x + e4.y) + (e4.z + e4.w);
    }
    l += __shfl_xor(l, 1, 8);
    l += __shfl_xor(l, 2, 8);
    l += __shfl_xor(l, 4, 8);
    __syncthreads();

    // ---- Phase D: PV accumulate. Lane: head h, dims (L&7)*4..+3 ----
    f32x4 acc = (f32x4){0.f, 0.f, 0.f, 0.f};
    const unsigned short* vb = Vb + 4 * L;
    for (int j = 0; j < nb; j += 4) {
        float4 wv = *(const float4*)&s_lds[h][j];
        int j0 = nbr[j], j1 = nbr[j + 1], j2 = nbr[j + 2], j3 = nbr[j + 3];
        uint2 r0 = *(const uint2*)(vb + (size_t)j0 * D_MODEL);
        uint2 r1 = *(const uint2*)(vb + (size_t)j1 * D_MODEL);
        uint2 r2 = *(const uint2*)(vb + (size_t)j2 * D_MODEL);
        uint2 r3 = *(const uint2*)(vb + (size_t)j3 * D_MODEL);
        acc[0] += wv.x * bf2f((unsigned short)(r0.x & 0xffff));
        acc[1] += wv.x * bf2f((unsigned short)(r0.x >> 16));
        acc[2] += wv.x * bf2f((unsigned short)(r0.y & 0xffff));
        acc[3] += wv.x * bf2f((unsigned short)(r0.y >> 16));
        acc[0] += wv.y * bf2f((unsigned short)(r1.x & 0xffff));
        acc[1] += wv.y * bf2f((unsigned short)(r1.x >> 16));
        acc[2] += wv.y * bf2f((unsigned short)(r1.y & 0xffff));
        acc[3] += wv.y * bf2f((unsigned short)(r1.y >> 16));
        acc[0] += wv.z * bf2f((unsigned short)(r2.x & 0xffff));
        acc[1] += wv.z * bf2f((unsigned short)(r2.x >> 16));
        acc[2] += wv.z * bf2f((unsigned short)(r2.y & 0xffff));
        acc[3] += wv.z * bf2f((unsigned short)(r2.y >> 16));
        acc[0] += wv.w * bf2f((unsigned short)(r3.x & 0xffff));
        acc[1] += wv.w * bf2f((unsigned short)(r3.x >> 16));
        acc[2] += wv.w * bf2f((unsigned short)(r3.y & 0xffff));
        acc[3] += wv.w * bf2f((unsigned short)(r3.y >> 16));
    }
    float rl = 1.f / l;
    ushort4 o;
    o.x = f2bf(acc[0] * rl); o.y = f2bf(acc[1] * rl);
    o.z = f2bf(acc[2] * rl); o.w = f2bf(acc[3] * rl);
    *(ushort4*)(Ob + (size_t)dst * D_MODEL + 4 * L) = o;
}

// ---------------------------------------------------------------------------
// Fused output GEMM + residual + bias + LayerNorm.
// BM=32, BN=256 (full row), BK=64 -> 128 blocks (proven best).
// ---------------------------------------------------------------------------
struct SMemO {
    union {
        struct { short A[32][72]; short B[256][72]; } st;
        float c[32][260];
    };
};

__global__ __launch_bounds__(256) void gemm_o_ln_kernel(
        const unsigned short* __restrict__ Ob, const unsigned short* __restrict__ Wob,
        const float* __restrict__ x, const float* __restrict__ bo,
        const float* __restrict__ gamma, const float* __restrict__ beta,
        float* __restrict__ out) {
    __shared__ SMemO sm;
    int by = blockIdx.x;
    int t = threadIdx.x;
    int wave = t >> 6, lane = t & 63;
    int rt = wave >> 1, cq = wave & 1;
    int lr = t >> 3;
    int lk = (t & 7) << 3;

    const unsigned short* Abase = Ob + ((size_t)(by * 32 + lr)) * D_MODEL + lk;
    int fm = lane & 15;
    int fk = (lane >> 4) << 3;

    f32x4 acc[8];
#pragma unroll
    for (int ct = 0; ct < 8; ++ct) acc[ct] = (f32x4){0.f, 0.f, 0.f, 0.f};

    for (int k0 = 0; k0 < D_MODEL; k0 += 64) {
        *(uint4*)&sm.st.A[lr][lk] = *(const uint4*)(Abase + k0);
#pragma unroll
        for (int j = 0; j < 8; ++j)
            *(uint4*)&sm.st.B[lr + 32 * j][lk] =
                *(const uint4*)(Wob + ((size_t)(lr + 32 * j)) * D_MODEL + k0 + lk);
        __syncthreads();
#pragma unroll
        for (int ks = 0; ks < 64; ks += 32) {
            bf16x8 af = *(const bf16x8*)&sm.st.A[rt * 16 + fm][ks + fk];
#pragma unroll
            for (int ct = 0; ct < 8; ++ct) {
                bf16x8 bf = *(const bf16x8*)&sm.st.B[cq * 128 + ct * 16 + fm][ks + fk];
                acc[ct] = __builtin_amdgcn_mfma_f32_16x16x32_bf16(af, bf, acc[ct], 0, 0, 0);
            }
        }
        __syncthreads();
    }

    int rr0 = rt * 16 + ((lane >> 4) << 2);
#pragma unroll
    for (int ct = 0; ct < 8; ++ct)
#pragma unroll
        for (int q = 0; q < 4; ++q)
            sm.c[rr0 + q][cq * 128 + ct * 16 + (lane & 15)] = acc[ct][q];
    __syncthreads();

    float4 bo4 = *(const float4*)(bo + lane * 4);
    float4 g4  = *(const float4*)(gamma + lane * 4);
    float4 be4 = *(const float4*)(beta + lane * 4);
#pragma unroll
    for (int rr = 0; rr < 8; ++rr) {
        int r = wave * 8 + rr;
        int grow = by * 32 + r;
        float4 p = *(const float4*)&sm.c[r][lane * 4];
        float4 xv = *(const float4*)(x + (size_t)grow * D_MODEL + lane * 4);
        float hx = p.x + xv.x + bo4.x;
        float hy = p.y + xv.y + bo4.y;
        float hz = p.z + xv.z + bo4.z;
        float hw = p.w + xv.w + bo4.w;
        float s  = (hx + hy) + (hz + hw);
        float s2 = (hx * hx + hy * hy) + (hz * hz + hw * hw);
#pragma unroll
        for (int o = 32; o; o >>= 1) {
            s  += __shfl_xor(s, o, 64);
            s2 += __shfl_xor(s2, o, 64);
        }
        float mu = s * (1.f / 256.f);
        float var = s2 * (1.f / 256.f) - mu * mu;
        float rstd = rsqrtf(var + 1e-5f);
        float4 o4;
        o4.x = (hx - mu) * rstd * g4.x + be4.x;
        o4.y = (hy - mu) * rstd * g4.y + be4.y;
        o4.z = (hz - mu) * rstd * g4.z + be4.z;
        o4.w = (hw - mu) * rstd * g4.w + be4.w;
        *(float4*)(out + (size_t)grow * D_MODEL + lane * 4) = o4;
    }
}

// ---------------------------------------------------------------------------
extern "C" void kernel_launch(void* const* d_in, const int* in_sizes, int n_in,
                              void* d_out, int out_size, void* d_ws, size_t ws_size,
                              hipStream_t stream) {
    const float* x     = (const float*)d_in[0];
    const int*   ei    = (const int*)  d_in[1];
    const float* Wq    = (const float*)d_in[2];
    const float* Wk    = (const float*)d_in[3];
    const float* Wv    = (const float*)d_in[4];
    const float* Wo    = (const float*)d_in[5];
    const float* bo    = (const float*)d_in[6];
    const float* gamma = (const float*)d_in[7];
    const float* beta  = (const float*)d_in[8];
    float* out = (float*)d_out;

    int n = in_sizes[0] / D_MODEL;   // 4096
    int E = in_sizes[1] / 2;         // 131072

    char* ws = (char*)d_ws;
    size_t off = 0;
    unsigned long long* mask = (unsigned long long*)(ws + off);
    size_t mask_bytes = (size_t)n * (n >> 6) * sizeof(unsigned long long); // 2 MiB
    off += mask_bytes;
    unsigned short* Wob = (unsigned short*)(ws + off); off += D_MODEL * D_MODEL * 2;
    unsigned short* Qb  = (unsigned short*)(ws + off); off += (size_t)n * D_MODEL * 2;
    unsigned short* Kb  = (unsigned short*)(ws + off); off += (size_t)n * D_MODEL * 2;
    unsigned short* Vb  = (unsigned short*)(ws + off); off += (size_t)n * D_MODEL * 2;
    unsigned short* Ob  = (unsigned short*)(ws + off); off += (size_t)n * D_MODEL * 2;

    // 1) zero the adjacency bitmap (diag handled inline in attn)
    hipMemsetAsync(mask, 0, mask_bytes, stream);

    // 2) fused QKV GEMM (inline fp32->bf16) + Wo convert + edge scatter
    int edge_blocks = (E + 255) / 256;       // 512
    qkv_edges_kernel<<<NGEMM + NCONV + edge_blocks, 256, 0, stream>>>(
        x, Wq, Wk, Wv, Wo, Qb, Kb, Vb, Wob, ei, mask, E, n);

    // 3) sparse attention: one wave per dst (proven two-pass structure)
    attn_kernel<<<n, 64, 0, stream>>>(Qb, Kb, Vb, mask, Ob, n);

    // 4) output GEMM + residual + LayerNorm
    gemm_o_ln_kernel<<<n / 32, 256, 0, stream>>>(Ob, Wob, x, bo, gamma, beta, out);
}